// Round 1
// baseline (89.672 us; speedup 1.0000x reference)
//
#include <hip/hip_runtime.h>
#include <math.h>

#define W 384
#define H 384
#define NB 32
#define NPIX (W*H)

#define XT 128          // columns per block (= threads)
#define YT 48           // rows per block
#define XTILES (W/XT)   // 3
#define YTILES (H/YT)   // 8
#define BLKS_PER_IMG (XTILES*YTILES)   // 24
#define NBLK (NB*BLKS_PER_IMG)         // 768
#define HALO 15
#define RING 32

__global__ __launch_bounds__(XT) void fused_loss_kernel(
    const float* __restrict__ pred,
    const float* __restrict__ mask,
    float* __restrict__ partials /* [NBLK][8] */)
{
    __shared__ float srow[XT + 2*HALO];     // 158 staged mask row (with col halo)
    __shared__ float ring3 [RING][XT];
    __shared__ float ring15[RING][XT];
    __shared__ float ring31[RING][XT];
    __shared__ float red[5][XT];

    const int blk   = blockIdx.x;
    const int b     = blk / BLKS_PER_IMG;
    const int t     = blk % BLKS_PER_IMG;
    const int ytile = t / XTILES;
    const int xtile = t % XTILES;
    const int tx    = threadIdx.x;
    const int x     = xtile*XT + tx;
    const int y0    = ytile*YT;

    const float* mplane = mask + (size_t)b*NPIX;
    const float* pplane = pred + (size_t)b*NPIX;

    // ---- init: fill ring with horizontal window sums for rows y0-15 .. y0+15
    for (int yy = y0-HALO; yy <= y0+HALO; ++yy) {
        const int slot = yy & (RING-1);
        if (yy < 0) {
            ring3[slot][tx]=0.f; ring15[slot][tx]=0.f; ring31[slot][tx]=0.f;
        } else {
            __syncthreads();   // protect srow from previous iteration's readers
            for (int i = tx; i < XT+2*HALO; i += XT) {
                int gx = xtile*XT - HALO + i;
                srow[i] = (gx >= 0 && gx < W) ? mplane[(size_t)yy*W + gx] : 0.f;
            }
            __syncthreads();
            const int c = tx + HALO;
            float s3 = srow[c-1]+srow[c]+srow[c+1];
            float s15 = s3;
            #pragma unroll
            for (int d=2; d<=7; ++d)  s15 += srow[c-d]+srow[c+d];
            float s31 = s15;
            #pragma unroll
            for (int d=8; d<=15; ++d) s31 += srow[c-d]+srow[c+d];
            ring3[slot][tx]=s3; ring15[slot][tx]=s15; ring31[slot][tx]=s31;
        }
    }

    // ---- initial vertical window sums centered at y0 (rows <0 are zeros in ring)
    float v3 = 0.f, v15 = 0.f, v31 = 0.f;
    #pragma unroll
    for (int d=-1; d<=1;  ++d) v3  += ring3 [(y0+d)&(RING-1)][tx];
    #pragma unroll
    for (int d=-7; d<=7;  ++d) v15 += ring15[(y0+d)&(RING-1)][tx];
    #pragma unroll
    for (int d=-15; d<=15; ++d) v31 += ring31[(y0+d)&(RING-1)][tx];

    const float inv9 = 1.0f/9.0f, inv225 = 1.0f/225.0f, inv961 = 1.0f/961.0f;
    float pw=0.f, pi=0.f, pu=0.f, pbce=0.f, pmae=0.f;

    for (int y = y0; y < y0+YT; ++y) {
        const float m = mplane[(size_t)y*W + x];
        const float p = pplane[(size_t)y*W + x];
        const float a3  = v3*inv9;
        const float a15 = v15*inv225;
        const float a31 = v31*inv961;
        const float w = fabsf(a3-m) + fabsf(a15-m) + fabsf(a31-m);
        const float weit = 1.0f + 0.5f*w*m;
        pw += weit;
        pi += p*m*weit;
        pu += (p+m)*weit;
        pbce -= m*logf(p) + (1.0f-m)*logf(1.0f-p);
        pmae += fabsf(p-m);

        // ---- slide vertical windows to center y+1; need row y+16 in ring
        const int ynew = y + 16;
        const int slot = ynew & (RING-1);
        if (ynew < H) {
            __syncthreads();
            for (int i = tx; i < XT+2*HALO; i += XT) {
                int gx = xtile*XT - HALO + i;
                srow[i] = (gx >= 0 && gx < W) ? mplane[(size_t)ynew*W + gx] : 0.f;
            }
            __syncthreads();
            const int c = tx + HALO;
            float s3 = srow[c-1]+srow[c]+srow[c+1];
            float s15 = s3;
            #pragma unroll
            for (int d=2; d<=7; ++d)  s15 += srow[c-d]+srow[c+d];
            float s31 = s15;
            #pragma unroll
            for (int d=8; d<=15; ++d) s31 += srow[c-d]+srow[c+d];
            ring3[slot][tx]=s3; ring15[slot][tx]=s15; ring31[slot][tx]=s31;
        } else {
            ring3[slot][tx]=0.f; ring15[slot][tx]=0.f; ring31[slot][tx]=0.f;
        }
        // ring data for column tx is produced and consumed only by thread tx
        v3  += ring3 [(y+2 )&(RING-1)][tx] - ring3 [(y-1 )&(RING-1)][tx];
        v15 += ring15[(y+8 )&(RING-1)][tx] - ring15[(y-7 )&(RING-1)][tx];
        v31 += ring31[(y+16)&(RING-1)][tx] - ring31[(y-15)&(RING-1)][tx];
    }

    // ---- deterministic block tree-reduction of the 5 partials
    red[0][tx]=pw; red[1][tx]=pi; red[2][tx]=pu; red[3][tx]=pbce; red[4][tx]=pmae;
    __syncthreads();
    for (int s = XT/2; s > 0; s >>= 1) {
        if (tx < s) {
            #pragma unroll
            for (int q = 0; q < 5; ++q) red[q][tx] += red[q][tx+s];
        }
        __syncthreads();
    }
    if (tx == 0) {
        float* o = partials + (size_t)blk*8;
        o[0]=red[0][0]; o[1]=red[1][0]; o[2]=red[2][0]; o[3]=red[3][0]; o[4]=red[4][0];
    }
}

__global__ __launch_bounds__(64) void finalize_kernel(
    const float* __restrict__ partials, float* __restrict__ out)
{
    const int lane = threadIdx.x;   // 64 threads = 1 wave

    // global sums (bce idx3, mae idx4) over all NBLK blocks, fp64, fixed order
    double bsum = 0.0, msum = 0.0;
    for (int j = lane; j < NBLK; j += 64) {
        bsum += (double)partials[(size_t)j*8 + 3];
        msum += (double)partials[(size_t)j*8 + 4];
    }
    #pragma unroll
    for (int s = 32; s > 0; s >>= 1) {
        bsum += __shfl_down(bsum, s);
        msum += __shfl_down(msum, s);
    }

    // per-image terms on lanes 0..31 (lanes >=32 contribute 0)
    double wiou = 0.0, ratio = 0.0;
    if (lane < NB) {
        double Sw = 0.0, Si = 0.0, Su = 0.0;
        for (int j = 0; j < BLKS_PER_IMG; ++j) {
            const float* pp = partials + (size_t)(lane*BLKS_PER_IMG + j)*8;
            Sw += (double)pp[0];
            Si += (double)pp[1];
            Su += (double)pp[2];
        }
        wiou  = 1.0 - Si/(Su - Si);
        ratio = Sw/(Sw - (double)NPIX);
    }
    #pragma unroll
    for (int s = 16; s > 0; s >>= 1) {
        wiou  += __shfl_down(wiou,  s);
        ratio += __shfl_down(ratio, s);
    }

    if (lane == 0) {
        const double tot = (double)NB * (double)NPIX;
        const double bce = bsum / tot;
        const double mae = msum / tot;
        // mean_b( wbce + wiou_b + wmae_b ), wbce_b == bce, wmae_b = mae*ratio_b
        const double loss = 0.7 * (bce + wiou/(double)NB + mae * ratio/(double)NB);
        out[0] = (float)loss;
    }
}

extern "C" void kernel_launch(void* const* d_in, const int* in_sizes, int n_in,
                              void* d_out, int out_size, void* d_ws, size_t ws_size,
                              hipStream_t stream) {
    const float* pred = (const float*)d_in[0];
    const float* mask = (const float*)d_in[1];
    float* out        = (float*)d_out;
    float* partials   = (float*)d_ws;   // NBLK*8 floats = 24 KB

    fused_loss_kernel<<<dim3(NBLK), dim3(XT), 0, stream>>>(pred, mask, partials);
    finalize_kernel<<<dim3(1), dim3(64), 0, stream>>>(partials, out);
}

// Round 2
// 85.857 us; speedup vs baseline: 1.0444x; 1.0444x over previous
//
#include <hip/hip_runtime.h>
#include <math.h>

#define W 384
#define H 384
#define NB 32
#define NPIX (W*H)
#define NROWS (NB*H)                    // 12288

// K2 tiling: single-wave blocks, 64 cols x YT rows
#define YT 16
#define XTILES 6                        // 384/64
#define YTILES (H/YT)                   // 24
#define BLKS_PER_IMG (XTILES*YTILES)    // 144
#define NBLK2 (NB*BLKS_PER_IMG)         // 4608

// K1: 4 rows per 256-thread block (1 row per wave)
#define K1_WAVES 4
#define NBLK1 (NROWS/K1_WAVES)          // 3072

// ---------------------------------------------------------------------------
// K1: row-wise inclusive prefix sums of mask -> P plane (in d_ws)
// ---------------------------------------------------------------------------
__global__ __launch_bounds__(256) void row_prefix_kernel(
    const float* __restrict__ m, float* __restrict__ P)
{
    __shared__ float buf[K1_WAVES][W];
    const int wave = threadIdx.x >> 6;
    const int lane = threadIdx.x & 63;
    const int row  = blockIdx.x * K1_WAVES + wave;   // < 12288 exactly

    const float* src = m + (size_t)row * W;
    float*       dst = P + (size_t)row * W;

    // per-lane 6 contiguous elements (8B-aligned float2 loads)
    const int i0 = lane * 6;
    const float2* s2 = (const float2*)(src + i0);
    const float2 q0 = s2[0], q1 = s2[1], q2 = s2[2];

    // serial in-lane prefix
    const float s0 = q0.x;
    const float s1 = s0 + q0.y;
    const float s2v = s1 + q1.x;
    const float s3 = s2v + q1.y;
    const float s4 = s3 + q2.x;
    const float s5 = s4 + q2.y;

    // wave inclusive scan of lane totals
    float s = s5;
    #pragma unroll
    for (int d = 1; d < 64; d <<= 1) {
        float t = __shfl_up(s, d);
        if (lane >= d) s += t;
    }
    const float base = s - s5;   // exclusive prefix of lane totals

    buf[wave][i0+0] = base + s0;
    buf[wave][i0+1] = base + s1;
    buf[wave][i0+2] = base + s2v;
    buf[wave][i0+3] = base + s3;
    buf[wave][i0+4] = base + s4;
    buf[wave][i0+5] = base + s5;
    __syncthreads();

    // coalesced 16B writeout: 96 float4 chunks per row
    const float4* bsrc = (const float4*)&buf[wave][0];
    float4*       bdst = (float4*)dst;
    bdst[lane] = bsrc[lane];
    if (lane < 32) bdst[lane + 64] = bsrc[lane + 64];
}

// ---------------------------------------------------------------------------
// K2: fused boundary-weight + loss partials. One wave per 64x16 tile.
// Horizontal box sums from P (2 loads + sub); vertical box sums slide in regs.
// ---------------------------------------------------------------------------
__global__ __launch_bounds__(64) void fused_main_kernel(
    const float* __restrict__ pred, const float* __restrict__ mask,
    const float* __restrict__ P, float* __restrict__ partials)
{
    __shared__ float C3[96], C15[96], C31[96];

    const int lane = threadIdx.x;
    const int blk  = blockIdx.x;
    const int b    = blk / BLKS_PER_IMG;
    const int rr   = blk % BLKS_PER_IMG;
    const int xt   = rr / YTILES;
    const int yt   = rr % YTILES;
    const int x0   = xt * 64;
    const int y0   = yt * YT;
    const int x    = x0 + lane;

    const float* Pimg = P    + (size_t)b * NPIX;
    const float* mimg = mask + (size_t)b * NPIX;
    const float* pimg = pred + (size_t)b * NPIX;

    // ---- init: per-column sums of P over the 3 row windows centered at y0.
    // slot c in [0,96) represents absolute column x0-16+c.
    {
        float a31=0.f, a15=0.f, a3=0.f, b31=0.f, b15=0.f, b3=0.f;
        const int c0 = x0 - 16 + lane;
        const int c1 = c0 + 64;
        const bool v0 = (c0 >= 0) && (c0 < W);
        const bool v1 = (lane < 32) && (c1 >= 0) && (c1 < W);
        #pragma unroll
        for (int dy = -15; dy <= 15; ++dy) {
            const int yy = y0 + dy;
            if (yy < 0 || yy >= H) continue;           // wave-uniform
            const float* Prow = Pimg + (size_t)yy * W;
            const float pa = v0 ? Prow[c0] : 0.0f;
            const float pb = v1 ? Prow[c1] : 0.0f;
            a31 += pa; b31 += pb;
            if (dy >= -7 && dy <= 7) { a15 += pa; b15 += pb; }
            if (dy >= -1 && dy <= 1) { a3  += pa; b3  += pb; }
        }
        C31[lane] = a31; C15[lane] = a15; C3[lane] = a3;
        if (lane < 32) { C31[lane+64] = b31; C15[lane+64] = b15; C3[lane+64] = b3; }
    }
    __syncthreads();

    // per-lane clamped column offsets (loop-invariant)
    const int  cr3  = min(x + 1,  W - 1);
    const int  cr15 = min(x + 7,  W - 1);
    const int  cr31 = min(x + 15, W - 1);
    const int  cl3  = x - 2;
    const int  cl15 = x - 8;
    const int  cl31 = x - 16;
    const bool p3   = (x >= 2);
    const bool p15  = (x >= 8);
    const bool p31  = (x >= 16);

    const int sbase = x0 - 16;
    float v3  = C3 [cr3  - sbase] - (p3  ? C3 [cl3  - sbase] : 0.0f);
    float v15 = C15[cr15 - sbase] - (p15 ? C15[cl15 - sbase] : 0.0f);
    float v31 = C31[cr31 - sbase] - (p31 ? C31[cl31 - sbase] : 0.0f);

    const float inv9 = 1.0f/9.0f, inv225 = 1.0f/225.0f, inv961 = 1.0f/961.0f;
    float pw=0.f, pi=0.f, pu=0.f, pbce=0.f, pmae=0.f;

    for (int y = y0; y < y0 + YT; ++y) {
        const float m = mimg[(size_t)y*W + x];
        const float p = pimg[(size_t)y*W + x];

        const float w = fabsf(v3*inv9 - m) + fabsf(v15*inv225 - m) + fabsf(v31*inv961 - m);
        const float weit = 1.0f + 0.5f*w*m;
        pw   += weit;
        pi   += p*m*weit;
        pu   += (p+m)*weit;
        pbce -= m*__logf(p) + (1.0f - m)*__logf(1.0f - p);
        pmae += fabsf(p - m);

        // slide all three vertical windows to center y+1
        {
            const int ya = y + 2, ys = y - 1;
            float add = 0.f, sub = 0.f;
            if (ya < H)  { const float* Pr = Pimg + (size_t)ya*W; add = Pr[cr3] - (p3 ? Pr[cl3] : 0.f); }
            if (ys >= 0) { const float* Pr = Pimg + (size_t)ys*W; sub = Pr[cr3] - (p3 ? Pr[cl3] : 0.f); }
            v3 += add - sub;
        }
        {
            const int ya = y + 8, ys = y - 7;
            float add = 0.f, sub = 0.f;
            if (ya < H)  { const float* Pr = Pimg + (size_t)ya*W; add = Pr[cr15] - (p15 ? Pr[cl15] : 0.f); }
            if (ys >= 0) { const float* Pr = Pimg + (size_t)ys*W; sub = Pr[cr15] - (p15 ? Pr[cl15] : 0.f); }
            v15 += add - sub;
        }
        {
            const int ya = y + 16, ys = y - 15;
            float add = 0.f, sub = 0.f;
            if (ya < H)  { const float* Pr = Pimg + (size_t)ya*W; add = Pr[cr31] - (p31 ? Pr[cl31] : 0.f); }
            if (ys >= 0) { const float* Pr = Pimg + (size_t)ys*W; sub = Pr[cr31] - (p31 ? Pr[cl31] : 0.f); }
            v31 += add - sub;
        }
    }

    // deterministic butterfly reduce across the wave
    #pragma unroll
    for (int off = 32; off >= 1; off >>= 1) {
        pw   += __shfl_xor(pw,   off);
        pi   += __shfl_xor(pi,   off);
        pu   += __shfl_xor(pu,   off);
        pbce += __shfl_xor(pbce, off);
        pmae += __shfl_xor(pmae, off);
    }
    if (lane == 0) {
        float* o = partials + (size_t)blk * 8;
        o[0]=pw; o[1]=pi; o[2]=pu; o[3]=pbce; o[4]=pmae;
    }
}

// ---------------------------------------------------------------------------
// K3: scalar finalize (1 wave, fp64, fixed order -> deterministic)
// ---------------------------------------------------------------------------
__global__ __launch_bounds__(64) void finalize_kernel(
    const float* __restrict__ partials, float* __restrict__ out)
{
    const int lane = threadIdx.x;

    double bsum = 0.0, msum = 0.0;
    for (int j = lane; j < NBLK2; j += 64) {
        bsum += (double)partials[(size_t)j*8 + 3];
        msum += (double)partials[(size_t)j*8 + 4];
    }
    #pragma unroll
    for (int s = 32; s > 0; s >>= 1) {
        bsum += __shfl_down(bsum, s);
        msum += __shfl_down(msum, s);
    }

    double wiou = 0.0, ratio = 0.0;
    if (lane < NB) {
        double Sw = 0.0, Si = 0.0, Su = 0.0;
        for (int j = 0; j < BLKS_PER_IMG; ++j) {
            const float* pp = partials + (size_t)(lane*BLKS_PER_IMG + j)*8;
            Sw += (double)pp[0];
            Si += (double)pp[1];
            Su += (double)pp[2];
        }
        wiou  = 1.0 - Si/(Su - Si);
        ratio = Sw/(Sw - (double)NPIX);
    }
    #pragma unroll
    for (int s = 16; s > 0; s >>= 1) {
        wiou  += __shfl_down(wiou,  s);
        ratio += __shfl_down(ratio, s);
    }

    if (lane == 0) {
        const double tot = (double)NB * (double)NPIX;
        const double bce = bsum / tot;
        const double mae = msum / tot;
        const double loss = 0.7 * (bce + wiou/(double)NB + mae * ratio/(double)NB);
        out[0] = (float)loss;
    }
}

extern "C" void kernel_launch(void* const* d_in, const int* in_sizes, int n_in,
                              void* d_out, int out_size, void* d_ws, size_t ws_size,
                              hipStream_t stream) {
    const float* pred = (const float*)d_in[0];
    const float* mask = (const float*)d_in[1];
    float* out        = (float*)d_out;

    // workspace layout: P plane (32*384*384 f32 = 18.87 MB), then partials
    float* P        = (float*)d_ws;
    float* partials = (float*)((char*)d_ws + (size_t)NB*NPIX*sizeof(float));

    row_prefix_kernel<<<dim3(NBLK1), dim3(256), 0, stream>>>(mask, P);
    fused_main_kernel<<<dim3(NBLK2), dim3(64), 0, stream>>>(pred, mask, P, partials);
    finalize_kernel<<<dim3(1), dim3(64), 0, stream>>>(partials, out);
}

// Round 3
// 53.967 us; speedup vs baseline: 1.6616x; 1.5909x over previous
//
#include <hip/hip_runtime.h>
#include <math.h>

#define W 384
#define H 384
#define NB 32
#define NPIX (W*H)

#define YT 16
#define SLABS (H/YT)            // 24 slabs per image
#define NBLK (NB*SLABS)         // 768 blocks, 1 wave each
#define RSTRIDE 416             // 16 zero left-pad + 384 + 16 total right-pad
#define RDEPTH 32

// ---------------------------------------------------------------------------
// Fused kernel: one wave per 384x16 slab. Row-prefix ring in LDS, vertical
// box sums slide in registers. No __syncthreads anywhere (single wave).
// ---------------------------------------------------------------------------
__global__ __launch_bounds__(64) void fused_kernel(
    const float* __restrict__ pred, const float* __restrict__ mask,
    float* __restrict__ partials)
{
    __shared__ float ring[RDEPTH][RSTRIDE];   // 53,248 B -> 3 blocks/CU

    const int lane = threadIdx.x;
    const int bid  = blockIdx.x;
    // XCD swizzle: all 24 slabs of an image live on one XCD (bid%8 == XCD)
    const int xcd  = bid & 7;
    const int k    = bid >> 3;                // 0..95
    const int b    = xcd + 8 * (k / SLABS);   // image
    const int slab = k % SLABS;
    const int y0   = slab * YT;
    const int x0   = lane * 6;                // 6 columns per lane (full row/wave)

    const float* mimg = mask + (size_t)b * NPIX;
    const float* pimg = pred + (size_t)b * NPIX;

    // zero the 16-word left pad of all 32 ring rows (stays zero forever)
    #pragma unroll
    for (int i = 0; i < 8; ++i) {
        const int idx = i * 64 + lane;        // 0..511
        ring[idx >> 4][idx & 15] = 0.0f;
    }

    // ---- helpers ----------------------------------------------------------
    auto loadrow = [&](const float* img, int r, float* v) {
        if (r >= 0 && r < H) {
            const float2* s = (const float2*)(img + (size_t)r * W + x0);
            float2 a = s[0], c = s[1], e = s[2];
            v[0]=a.x; v[1]=a.y; v[2]=c.x; v[3]=c.y; v[4]=e.x; v[5]=e.y;
        } else {
            #pragma unroll
            for (int j = 0; j < 6; ++j) v[j] = 0.0f;
        }
    };

    // scan preloaded mask-row values and write prefix row into the ring
    auto scan_write = [&](int r, const float* v) {
        const int slot = r & (RDEPTH - 1);
        const float s0 = v[0];
        const float s1 = s0 + v[1];
        const float s2 = s1 + v[2];
        const float s3 = s2 + v[3];
        const float s4 = s3 + v[4];
        const float s5 = s4 + v[5];
        float s = s5;                          // wave inclusive scan of totals
        #pragma unroll
        for (int d = 1; d < 64; d <<= 1) {
            float t = __shfl_up(s, d);
            if (lane >= d) s += t;
        }
        const float base = s - s5;
        float* row = &ring[slot][16 + x0];
        row[0]=base+s0; row[1]=base+s1; row[2]=base+s2;
        row[3]=base+s3; row[4]=base+s4; row[5]=base+s5;
        const float T = __shfl(s, 63);         // row total -> replicate pad
        if (lane < 16) ring[slot][400 + lane] = T;
    };

    // horizontal box-sum vector for radius roff from ring row r
    auto hvec = [&](int r, int roff, float* h) {
        const float* row = &ring[r & (RDEPTH - 1)][16];
        const float* R = row + x0 + roff;      // P[min(x+roff,383)] via pad
        const float* L = row + x0 - roff - 1;  // P[x-roff-1], zero pad for <0
        #pragma unroll
        for (int j = 0; j < 6; ++j) h[j] = R[j] - L[j];
    };

    // ---- warmup: ingest rows y0-16 .. y0+14, build va(y0-1) ----------------
    float va3[6], va15[6], va31[6];
    #pragma unroll
    for (int j = 0; j < 6; ++j) { va3[j]=0.f; va15[j]=0.f; va31[j]=0.f; }

    for (int r = y0 - 16; r <= y0 + 14; ++r) {
        float v[6];
        loadrow(mimg, r, v);
        scan_write(r, v);
        if (r >= 0) {
            float h[6];
            if (r >= y0 - 2 && r <= y0) {
                hvec(r, 1, h);
                #pragma unroll
                for (int j = 0; j < 6; ++j) va3[j] += h[j];
            }
            if (r >= y0 - 8 && r <= y0 + 6) {
                hvec(r, 7, h);
                #pragma unroll
                for (int j = 0; j < 6; ++j) va15[j] += h[j];
            }
            hvec(r, 15, h);                    // [y0-16, y0+14] == all rows
            #pragma unroll
            for (int j = 0; j < 6; ++j) va31[j] += h[j];
        }
    }

    // ---- main loop over the slab's 16 rows --------------------------------
    const float inv9 = 1.0f/9.0f, inv225 = 1.0f/225.0f, inv961 = 1.0f/961.0f;
    float pw=0.f, pin=0.f, pun=0.f, pbce=0.f, pmae=0.f;

    float nv[6];
    loadrow(mimg, y0 + 15, nv);                // preloaded ingest row

    for (int y = y0; y < y0 + YT; ++y) {
        float nv2[6], pv[6], mv[6];
        loadrow(mimg, y + 16, nv2);            // prefetch next ingest
        loadrow(pimg, y, pv);
        loadrow(mimg, y, mv);                  // L2-hot (ingested 15 rows ago)

        scan_write(y + 15, nv);                // ingest row y+15

        float ha[6], hs[6];
        hvec(y + 1, 1, ha);  hvec(y - 2, 1, hs);
        #pragma unroll
        for (int j = 0; j < 6; ++j) va3[j]  += ha[j] - hs[j];
        hvec(y + 7, 7, ha);  hvec(y - 8, 7, hs);
        #pragma unroll
        for (int j = 0; j < 6; ++j) va15[j] += ha[j] - hs[j];
        hvec(y + 15, 15, ha); hvec(y - 16, 15, hs);
        #pragma unroll
        for (int j = 0; j < 6; ++j) va31[j] += ha[j] - hs[j];

        #pragma unroll
        for (int j = 0; j < 6; ++j) {
            const float m = mv[j], p = pv[j];
            const float w = fabsf(va3[j]*inv9  - m)
                          + fabsf(va15[j]*inv225 - m)
                          + fabsf(va31[j]*inv961 - m);
            const float weit = 1.0f + 0.5f*w*m;
            pw   += weit;
            pin  += p*m*weit;
            pun  += (p+m)*weit;
            pbce -= m*__logf(p) + (1.0f - m)*__logf(1.0f - p);
            pmae += fabsf(p - m);
        }

        #pragma unroll
        for (int j = 0; j < 6; ++j) nv[j] = nv2[j];
    }

    // ---- deterministic butterfly reduce + write block partials ------------
    #pragma unroll
    for (int off = 32; off >= 1; off >>= 1) {
        pw   += __shfl_xor(pw,   off);
        pin  += __shfl_xor(pin,  off);
        pun  += __shfl_xor(pun,  off);
        pbce += __shfl_xor(pbce, off);
        pmae += __shfl_xor(pmae, off);
    }
    if (lane == 0) {
        float* o = partials + (size_t)(b * SLABS + slab) * 8;
        o[0]=pw; o[1]=pin; o[2]=pun; o[3]=pbce; o[4]=pmae;
    }
}

// ---------------------------------------------------------------------------
// Finalize: 1 wave, fp64, fixed order -> deterministic scalar
// ---------------------------------------------------------------------------
__global__ __launch_bounds__(64) void finalize_kernel(
    const float* __restrict__ partials, float* __restrict__ out)
{
    const int lane = threadIdx.x;

    double bsum = 0.0, msum = 0.0;
    for (int j = lane; j < NBLK; j += 64) {
        bsum += (double)partials[(size_t)j*8 + 3];
        msum += (double)partials[(size_t)j*8 + 4];
    }
    #pragma unroll
    for (int s = 32; s > 0; s >>= 1) {
        bsum += __shfl_down(bsum, s);
        msum += __shfl_down(msum, s);
    }

    double wiou = 0.0, ratio = 0.0;
    if (lane < NB) {
        double Sw = 0.0, Si = 0.0, Su = 0.0;
        for (int j = 0; j < SLABS; ++j) {
            const float* pp = partials + (size_t)(lane*SLABS + j)*8;
            Sw += (double)pp[0];
            Si += (double)pp[1];
            Su += (double)pp[2];
        }
        wiou  = 1.0 - Si/(Su - Si);
        ratio = Sw/(Sw - (double)NPIX);
    }
    #pragma unroll
    for (int s = 16; s > 0; s >>= 1) {
        wiou  += __shfl_down(wiou,  s);
        ratio += __shfl_down(ratio, s);
    }

    if (lane == 0) {
        const double tot = (double)NB * (double)NPIX;
        const double bce = bsum / tot;
        const double mae = msum / tot;
        const double loss = 0.7 * (bce + wiou/(double)NB + mae * ratio/(double)NB);
        out[0] = (float)loss;
    }
}

extern "C" void kernel_launch(void* const* d_in, const int* in_sizes, int n_in,
                              void* d_out, int out_size, void* d_ws, size_t ws_size,
                              hipStream_t stream) {
    const float* pred = (const float*)d_in[0];
    const float* mask = (const float*)d_in[1];
    float* out        = (float*)d_out;
    float* partials   = (float*)d_ws;          // 768*8*4 B = 24 KB

    fused_kernel<<<dim3(NBLK), dim3(64), 0, stream>>>(pred, mask, partials);
    finalize_kernel<<<dim3(1), dim3(64), 0, stream>>>(partials, out);
}